// Round 17
// baseline (535.860 us; speedup 1.0000x reference)
//
#include <hip/hip_runtime.h>

#define NN   100000
#define NNZq 3200000
#define NE   1000000
#define NBUCK 782        // ceil(NN/128) buckets of 128 rows
#define NBLK  625        // chunks over the COO arrays
#define CHUNK 5120       // NBLK*CHUNK == NNZq
#define BCAP 5120        // k_csr LDS stage capacity
#define RSTR 100032      // int stride between pos/neg rowptr arrays
#define NEMB 1563        // embed blocks

typedef float f32x4 __attribute__((ext_vector_type(4)));
typedef unsigned short ushort_t;
typedef ushort_t us4 __attribute__((ext_vector_type(4)));
typedef ushort_t us8 __attribute__((ext_vector_type(8)));
typedef __bf16 bf8 __attribute__((ext_vector_type(8)));
typedef _Float16 f16;
typedef f16 h8 __attribute__((ext_vector_type(8)));

__device__ __forceinline__ ushort_t f2bf(float f){
  unsigned u = __builtin_bit_cast(unsigned, f);
  u += 0x7FFFu + ((u >> 16) & 1u);
  return (ushort_t)(u >> 16);
}
__device__ __forceinline__ float bf2f(ushort_t s){
  unsigned u = ((unsigned)s) << 16;
  return __builtin_bit_cast(float, u);
}
__device__ __forceinline__ float sigm(float x){ return 1.f/(1.f + __expf(-x)); }
__device__ __forceinline__ float tanh_f(float x){ return 1.f - 2.f/(1.f + __expf(2.f*x)); }

__device__ __forceinline__ f32x4 MFMA(bf8 a, bf8 b, f32x4 c){
  return __builtin_amdgcn_mfma_f32_16x16x32_bf16(a, b, c, 0, 0, 0);
}
__device__ __forceinline__ f32x4 MFMA16(h8 a, h8 b, f32x4 c){
  return __builtin_amdgcn_mfma_f32_16x16x32_f16(a, b, c, 0, 0, 0);
}
__device__ __forceinline__ h8 habs8(h8 a){
  us8 u = __builtin_bit_cast(us8, a);
  #pragma unroll
  for (int j = 0; j < 8; j++) u[j] = u[j] & 0x7FFF;
  return __builtin_bit_cast(h8, u);
}
// bijective XCD-contiguous chunk swizzle (NBLK=625: q=78, r=1)
__device__ __forceinline__ int swz_chunk(int bid){
  int g = bid & 7, j = bid >> 3;
  const int q = NBLK >> 3, r = NBLK & 7;
  int base = (g < r) ? g*(q+1) : r*(q+1) + (g - r)*q;
  return base + j;
}
// convert 8 floats to split-bf16 hi/lo fragments
__device__ __forceinline__ void splitbf(const float* fv, bf8& hi8, bf8& lo8){
  us8 hi, lo;
  #pragma unroll
  for (int j = 0; j < 8; j++){
    ushort_t hh = f2bf(fv[j]); hi[j] = hh; lo[j] = f2bf(fv[j] - bf2f(hh));
  }
  hi8 = __builtin_bit_cast(bf8, hi);
  lo8 = __builtin_bit_cast(bf8, lo);
}

// ---------------- weight prep ----------------
__global__ __launch_bounds__(256) void k_prep(
    const float* __restrict__ W_in, const float* __restrict__ W_gate,
    const float* __restrict__ W_out, const float* __restrict__ W_e1,
    ushort_t* __restrict__ Wt_in, ushort_t* __restrict__ Wgt,
    ushort_t* __restrict__ Wot, f16* __restrict__ Wt_e1h)
{
  int tid = blockIdx.x * 256 + threadIdx.x;
  int stride = gridDim.x * 256;
  for (int i = tid; i < 64*256; i += stride){
    int c = i >> 8, k = i & 255;
    float f = W_in[k*64 + c];
    ushort_t hi = f2bf(f); ushort_t lo = f2bf(f - bf2f(hi));
    Wt_in[c*512 + k] = hi; Wt_in[c*512 + 256 + k] = lo;
  }
  for (int i = tid; i < 2*64*128; i += stride){
    int hop = i >> 13, r = i & 8191; int c = r >> 7, k = r & 127;
    float f = W_gate[hop*8192 + k*64 + c];
    ushort_t hi = f2bf(f); ushort_t lo = f2bf(f - bf2f(hi));
    Wgt[hop*16384 + c*256 + k] = hi; Wgt[hop*16384 + c*256 + 128 + k] = lo;
  }
  for (int i = tid; i < 2*64*64; i += stride){
    int hop = i >> 12, r = i & 4095; int c = r >> 6, k = r & 63;
    float f = W_out[hop*4096 + k*64 + c];
    ushort_t hi = f2bf(f); ushort_t lo = f2bf(f - bf2f(hi));
    Wot[hop*8192 + c*128 + k] = hi; Wot[hop*8192 + c*128 + 64 + k] = lo;
  }
  for (int i = tid; i < 64*288; i += stride){
    int c = i / 288, k = i - c*288;
    float f = (k < 272) ? W_e1[k*64 + c] : 0.f;
    Wt_e1h[c*288 + k] = (f16)f;
  }
}

// ---------------- counting sort, pass 1 (int4 loads) ----------------
__global__ __launch_bounds__(256) void k_cnt(
    const int* __restrict__ rows_p, const int* __restrict__ rows_n,
    int* __restrict__ blkhist)
{
  __shared__ int hist[NBUCK];
  const int* rows = blockIdx.y ? rows_n : rows_p;
  int* bh = blkhist + (size_t)blockIdx.y * (NBLK*NBUCK);
  int t = threadIdx.x;
  for (int i = t; i < NBUCK; i += 256) hist[i] = 0;
  __syncthreads();
  const int4* r4 = (const int4*)(rows + blockIdx.x * CHUNK);
  #pragma unroll
  for (int k = 0; k < CHUNK/1024; k++){
    int4 v = r4[t + k*256];
    atomicAdd(&hist[v.x >> 7], 1);
    atomicAdd(&hist[v.y >> 7], 1);
    atomicAdd(&hist[v.z >> 7], 1);
    atomicAdd(&hist[v.w >> 7], 1);
  }
  __syncthreads();
  for (int i = t; i < NBUCK; i += 256) bh[blockIdx.x * NBUCK + i] = hist[i];
}

__global__ __launch_bounds__(256) void k_scanA(int* __restrict__ blkhist, int* __restrict__ btot)
{
  __shared__ int sh[256];
  int b = blockIdx.x;
  int* bh = blkhist + (size_t)blockIdx.y * (NBLK*NBUCK);
  int t = threadIdx.x;
  int carry = 0;
  for (int k0 = 0; k0 < NBLK; k0 += 256){
    int idx = k0 + t;
    int v = (idx < NBLK) ? bh[idx*NBUCK + b] : 0;
    sh[t] = v; __syncthreads();
    for (int off = 1; off < 256; off <<= 1){
      int xx = (t >= off) ? sh[t-off] : 0;
      __syncthreads();
      sh[t] += xx;
      __syncthreads();
    }
    if (idx < NBLK) bh[idx*NBUCK + b] = carry + sh[t] - v;
    carry += sh[255];
    __syncthreads();
  }
  if (t == 0) btot[blockIdx.y*NBUCK + b] = carry;
}

__global__ __launch_bounds__(1024) void k_scanB(const int* __restrict__ btot, int* __restrict__ bbase)
{
  __shared__ int sh[1024];
  int y = blockIdx.y;
  int t = threadIdx.x;
  int v = (t < NBUCK) ? btot[y*NBUCK + t] : 0;
  sh[t] = v; __syncthreads();
  for (int off = 1; off < 1024; off <<= 1){
    int xx = (t >= off) ? sh[t-off] : 0;
    __syncthreads();
    sh[t] += xx;
    __syncthreads();
  }
  if (t < NBUCK) bbase[y*(NBUCK+1) + t] = sh[t] - v;
  if (t == 0) bbase[y*(NBUCK+1) + NBUCK] = sh[1023];
}

// ---------------- fused scat + embed, INTERLEAVED block assignment ----------------
// bid < 2500: even -> scat(bid/2), odd -> embed(bid/2); bid >= 2500 -> embed(1250+bid-2500)
// scat LDS: stage 40960 | hcnt 3136 | lcur 3136 | sh 1024 = 48256 B
// embed LDS: Bl[64][520] ushort = 66560 B (full hi+lo)
#define SMEM_BYTES 66560
__global__ __launch_bounds__(256) void k_scatembed(
    // scat args
    const int* __restrict__ rows_p, const int* __restrict__ cols_p, const float* __restrict__ vals_p,
    const int* __restrict__ rows_n, const int* __restrict__ cols_n, const float* __restrict__ vals_n,
    const int* __restrict__ blkhist, const int* __restrict__ bbase,
    uint2* __restrict__ tmp_p, uint2* __restrict__ tmp_n,
    // embed args
    const float* __restrict__ x, const ushort_t* __restrict__ Wt,
    const float* __restrict__ b_in, f16* __restrict__ h16)
{
  __shared__ __align__(16) char smem[SMEM_BYTES];
  int t = threadIdx.x;
  int bid = blockIdx.x;
  int scat_id = -1, emb_id = -1;
  if (bid < 2*NBLK*2){           // 2500
    if ((bid & 1) == 0) scat_id = bid >> 1;     // 0..1249
    else                emb_id  = bid >> 1;     // 0..1249
  } else {
    emb_id = 2*NBLK + (bid - 2*NBLK*2);         // 1250..1562
  }
  if (scat_id >= 0){
    // ---------- scat ----------
    uint2* stage = (uint2*)smem;
    int* hcnt = (int*)(smem + 40960);
    int* lcur = (int*)(smem + 40960 + 3136);
    int* sh   = (int*)(smem + 40960 + 3136*2);
    int y = (scat_id >= NBLK) ? 1 : 0;
    int bx = scat_id - y*NBLK;
    const int* rows; const int* cols; const float* vals; uint2* tmp;
    if (y == 0){ rows = rows_p; cols = cols_p; vals = vals_p; tmp = tmp_p; }
    else       { rows = rows_n; cols = cols_n; vals = vals_n; tmp = tmp_n; }
    int chunk = swz_chunk(bx);
    const int* bh = blkhist + (size_t)y*(NBLK*NBUCK) + (size_t)chunk*NBUCK;
    const int* bb = bbase + y*(NBUCK+1);
    for (int i = t; i < NBUCK; i += 256) hcnt[i] = 0;
    __syncthreads();
    int base = chunk * CHUNK;
    int rl[CHUNK/256];
    #pragma unroll
    for (int k = 0; k < CHUNK/256; k++){
      int r = rows[base + t + k*256];
      rl[k] = r;
      atomicAdd(&hcnt[r >> 7], 1);
    }
    __syncthreads();
    int carry = 0;
    for (int k0 = 0; k0 < 1024; k0 += 256){
      int idx = k0 + t;
      int v = (idx < NBUCK) ? hcnt[idx] : 0;
      sh[t] = v; __syncthreads();
      for (int off = 1; off < 256; off <<= 1){
        int xx = (t >= off) ? sh[t-off] : 0;
        __syncthreads();
        sh[t] += xx;
        __syncthreads();
      }
      if (idx < NBUCK) lcur[idx] = carry + sh[t] - v;
      carry += sh[255];
      __syncthreads();
    }
    for (int i = t; i < NBUCK; i += 256) hcnt[i] = bb[i] + bh[i] - lcur[i];
    __syncthreads();
    #pragma unroll
    for (int k = 0; k < CHUNK/256; k++){
      int i = base + t + k*256;
      int r = rl[k];
      int pos = atomicAdd(&lcur[r >> 7], 1);
      f16 hv = (f16)vals[i];
      uint2 ent;
      ent.x = (unsigned)cols[i] | ((unsigned)(r & 127) << 17);
      ent.y = (unsigned)__builtin_bit_cast(ushort_t, hv) | ((unsigned)(r >> 7) << 16);
      stage[pos] = ent;
    }
    __syncthreads();
    for (int k = t; k < CHUNK; k += 256){
      uint2 ent = stage[k];
      int bkt = ent.y >> 16;
      tmp[hcnt[bkt] + k] = ent;
    }
  } else {
    // ---------- embed (full W_in^T hi|lo in LDS, r14-proven) ----------
    ushort_t (*Bl)[520] = (ushort_t(*)[520])smem;
    int r0 = emb_id * 64;
    const uint4* W4 = (const uint4*)Wt;
    #pragma unroll
    for (int n = 0; n < 16; n++){
      int i = t + n*256;
      int row = i >> 6, kc = i & 63;
      *(uint4*)&Bl[row][kc*8] = W4[i];
    }
    int w = t >> 6, l = t & 63;
    int lr = l & 15, lg = l >> 4;
    int row = r0 + w*16 + lr;
    bool ok = row < NN;
    const float* xr = x + (size_t)row*256 + lg*8;
    bf8 ahi[8], alo[8];
    #pragma unroll
    for (int ks = 0; ks < 8; ks++){
      float4 v0 = make_float4(0.f,0.f,0.f,0.f), v1 = v0;
      if (ok){
        v0 = *(const float4*)(xr + ks*32);
        v1 = *(const float4*)(xr + ks*32 + 4);
      }
      float fv[8] = {v0.x,v0.y,v0.z,v0.w,v1.x,v1.y,v1.z,v1.w};
      splitbf(fv, ahi[ks], alo[ks]);
    }
    __syncthreads();
    f32x4 z = {0.f,0.f,0.f,0.f};
    f32x4 acc[4] = {z,z,z,z};
    #pragma unroll
    for (int ks = 0; ks < 24; ks++){
      bf8 a = (ks < 8) ? ahi[ks] : (ks < 16) ? alo[ks-8] : ahi[ks-16];
      int boff = (ks < 16) ? (ks & 7)*32 : 256 + (ks-16)*32;
      #pragma unroll
      for (int cg = 0; cg < 4; cg++){
        bf8 b = *(const bf8*)&Bl[16*cg + lr][boff + 8*lg];
        acc[cg] = MFMA(a, b, acc[cg]);
      }
    }
    #pragma unroll
    for (int cg = 0; cg < 4; cg++){
      int col = 16*cg + lr;
      float bi = b_in[col];
      #pragma unroll
      for (int reg = 0; reg < 4; reg++){
        int rr = r0 + w*16 + 4*lg + reg;
        if (rr < NN) h16[(size_t)rr*64 + col] = (f16)tanh_f(acc[cg][reg] + bi);
      }
    }
  }
}

// ---------------- pass 4: bucket-grouped -> row-sorted 4B CSR + rowptr ----------------
// CSR entry: (col & 0x1FFFF) | (f16bits(val) << 17)
__global__ __launch_bounds__(256) void k_csr(
    const int* __restrict__ bbase, const uint2* __restrict__ tmp_p, const uint2* __restrict__ tmp_n,
    unsigned* __restrict__ csr_p, unsigned* __restrict__ csr_n, int* __restrict__ rowptr)
{
  __shared__ int cnt[128];
  __shared__ int sh[128];
  __shared__ int lcur[128];
  __shared__ unsigned stage[BCAP];
  int y = blockIdx.y, b = blockIdx.x;
  const uint2* tmp = y ? tmp_n : tmp_p;
  unsigned* csr = y ? csr_n : csr_p;
  int* rp = rowptr + (size_t)y * RSTR;
  const int* bb = bbase + y*(NBUCK+1);
  int s = bb[b], e = bb[b+1];
  int n = e - s;
  int t = threadIdx.x;
  if (t < 128) cnt[t] = 0;
  __syncthreads();
  for (int k = t; k < n; k += 256)
    atomicAdd(&cnt[tmp[s + k].x >> 17], 1);
  __syncthreads();
  if (t < 128) sh[t] = cnt[t];
  __syncthreads();
  for (int off = 1; off < 128; off <<= 1){
    int xx = (t >= off && t < 128) ? sh[t-off] : 0;
    __syncthreads();
    if (t < 128) sh[t] += xx;
    __syncthreads();
  }
  if (t < 128){
    int excl = sh[t] - cnt[t];
    lcur[t] = excl;
    int row = b*128 + t;
    if (row < NN) rp[row] = s + excl;
  }
  if (b == NBUCK-1 && t == 0) rp[NN] = e;
  __syncthreads();
  if (n <= BCAP){
    for (int k = t; k < n; k += 256){
      uint2 ent = tmp[s + k];
      int rloc = ent.x >> 17;
      int pos = atomicAdd(&lcur[rloc], 1);
      stage[pos] = (ent.x & 0x1FFFF) | ((ent.y & 0xFFFFu) << 17);
    }
    __syncthreads();
    for (int k = t; k < n; k += 256) csr[s + k] = stage[k];
  } else {
    for (int k = t; k < n; k += 256){
      uint2 ent = tmp[s + k];
      int rloc = ent.x >> 17;
      int pos = atomicAdd(&lcur[rloc], 1);
      csr[s + pos] = (ent.x & 0x1FFFF) | ((ent.y & 0xFFFFu) << 17);
    }
  }
}

// ---------------- SpMM fused pos+neg: one wave per row, 4B entries, fp16 gathers ----------------
__device__ __forceinline__ float ent_val(unsigned e){
  return (float)__builtin_bit_cast(f16, (ushort_t)(e >> 17));
}
__global__ __launch_bounds__(256) void k_spmm2(
    const int* __restrict__ rp_p, const unsigned* __restrict__ csr_p,
    const int* __restrict__ rp_n, const unsigned* __restrict__ csr_n,
    const f16* __restrict__ h16, float* __restrict__ hp, float* __restrict__ hn)
{
  int w = __builtin_amdgcn_readfirstlane(blockIdx.x * 4 + (threadIdx.x >> 6));
  int l = threadIdx.x & 63;
  int sp = __builtin_amdgcn_readfirstlane(rp_p[w]);
  int ep = __builtin_amdgcn_readfirstlane(rp_p[w+1]);
  int sn = __builtin_amdgcn_readfirstlane(rp_n[w]);
  int en = __builtin_amdgcn_readfirstlane(rp_n[w+1]);
  float ap = 0.f, an = 0.f;
  int i = sp, j = sn;
  while (i + 4 <= ep && j + 4 <= en){
    unsigned q0 = csr_p[i], q1 = csr_p[i+1], q2 = csr_p[i+2], q3 = csr_p[i+3];
    unsigned r0 = csr_n[j], r1 = csr_n[j+1], r2 = csr_n[j+2], r3 = csr_n[j+3];
    float g0 = (float)h16[(q0 & 0x1FFFF)*64 + l], g1 = (float)h16[(q1 & 0x1FFFF)*64 + l];
    float g2 = (float)h16[(q2 & 0x1FFFF)*64 + l], g3 = (float)h16[(q3 & 0x1FFFF)*64 + l];
    float f0 = (float)h16[(r0 & 0x1FFFF)*64 + l], f1 = (float)h16[(r1 & 0x1FFFF)*64 + l];
    float f2 = (float)h16[(r2 & 0x1FFFF)*64 + l], f3 = (float)h16[(r3 & 0x1FFFF)*64 + l];
    ap += ent_val(q0) * g0;
    ap += ent_val(q1) * g1;
    ap += ent_val(q2) * g2;
    ap += ent_val(q3) * g3;
    an += ent_val(r0) * f0;
    an += ent_val(r1) * f1;
    an += ent_val(r2) * f2;
    an += ent_val(r3) * f3;
    i += 4; j += 4;
  }
  for (; i + 4 <= ep; i += 4){
    unsigned q0 = csr_p[i], q1 = csr_p[i+1], q2 = csr_p[i+2], q3 = csr_p[i+3];
    float g0 = (float)h16[(q0 & 0x1FFFF)*64 + l], g1 = (float)h16[(q1 & 0x1FFFF)*64 + l];
    float g2 = (float)h16[(q2 & 0x1FFFF)*64 + l], g3 = (float)h16[(q3 & 0x1FFFF)*64 + l];
    ap += ent_val(q0) * g0;
    ap += ent_val(q1) * g1;
    ap += ent_val(q2) * g2;
    ap += ent_val(q3) * g3;
  }
  for (; i < ep; i++){
    unsigned q = csr_p[i];
    ap += ent_val(q) * (float)h16[(q & 0x1FFFF)*64 + l];
  }
  for (; j + 4 <= en; j += 4){
    unsigned r0 = csr_n[j], r1 = csr_n[j+1], r2 = csr_n[j+2], r3 = csr_n[j+3];
    float f0 = (float)h16[(r0 & 0x1FFFF)*64 + l], f1 = (float)h16[(r1 & 0x1FFFF)*64 + l];
    float f2 = (float)h16[(r2 & 0x1FFFF)*64 + l], f3 = (float)h16[(r3 & 0x1FFFF)*64 + l];
    an += ent_val(r0) * f0;
    an += ent_val(r1) * f1;
    an += ent_val(r2) * f2;
    an += ent_val(r3) * f3;
  }
  for (; j < en; j++){
    unsigned r = csr_n[j];
    an += ent_val(r) * (float)h16[(r & 0x1FFFF)*64 + l];
  }
  hp[w*64 + l] = ap;
  hn[w*64 + l] = an;
}

// ---------------- gate+out per hop: reg-A split-bf16 MFMA, writes fp16 h ----------------
__global__ __launch_bounds__(256) void k_gateout(
    const float* __restrict__ hp, const float* __restrict__ hn,
    const ushort_t* __restrict__ Wgt_h, const ushort_t* __restrict__ Wot_h,
    const float* __restrict__ bg, const float* __restrict__ bo,
    f16* __restrict__ h16)
{
  __shared__ ushort_t Bg[64][264];
  __shared__ ushort_t Ao[64][136];
  __shared__ ushort_t Bo[64][136];
  int t = threadIdx.x;
  int r0 = blockIdx.x * 64;
  const uint4* Wg4 = (const uint4*)Wgt_h;
  #pragma unroll
  for (int n = 0; n < 8; n++){
    int i = t + n*256; int row = i >> 5, kc = i & 31;
    *(uint4*)&Bg[row][kc*8] = Wg4[i];
  }
  const uint4* Wo4 = (const uint4*)Wot_h;
  #pragma unroll
  for (int n = 0; n < 4; n++){
    int i = t + n*256; int row = i >> 4, kc = i & 15;
    *(uint4*)&Bo[row][kc*8] = Wo4[i];
  }
  int w = t >> 6, l = t & 63;
  int lr = l & 15, lg = l >> 4;
  int arow = r0 + w*16 + lr;
  bool ok = arow < NN;
  const float* hpr = hp + (size_t)arow*64 + lg*8;
  const float* hnr = hn + (size_t)arow*64 + lg*8;
  bf8 ahi[4], alo[4];
  #pragma unroll
  for (int ks = 0; ks < 4; ks++){
    const float* src = (ks < 2) ? hpr + ks*32 : hnr + (ks-2)*32;
    float4 v0 = make_float4(0.f,0.f,0.f,0.f), v1 = v0;
    if (ok){
      v0 = *(const float4*)src;
      v1 = *(const float4*)(src + 4);
    }
    float fv[8] = {v0.x,v0.y,v0.z,v0.w,v1.x,v1.y,v1.z,v1.w};
    splitbf(fv, ahi[ks], alo[ks]);
  }
  __syncthreads();
  f32x4 z = {0.f,0.f,0.f,0.f};
  f32x4 acc[4] = {z,z,z,z};
  #pragma unroll
  for (int ks = 0; ks < 12; ks++){
    bf8 a = (ks < 4) ? ahi[ks] : (ks < 8) ? alo[ks-4] : ahi[ks-8];
    int boff = (ks < 8) ? (ks & 3)*32 : 128 + (ks-8)*32;
    #pragma unroll
    for (int cg = 0; cg < 4; cg++){
      bf8 b = *(const bf8*)&Bg[16*cg + lr][boff + 8*lg];
      acc[cg] = MFMA(a, b, acc[cg]);
    }
  }
  #pragma unroll
  for (int cg = 0; cg < 4; cg++){
    int col = 16*cg + lr;
    float bgv = bg[col];
    #pragma unroll
    for (int reg = 0; reg < 4; reg++){
      int lrow = w*16 + 4*lg + reg;
      int rr = r0 + lrow;
      float hpv = 0.f, hnv = 0.f;
      if (rr < NN){
        hpv = hp[(size_t)rr*64 + col];
        hnv = hn[(size_t)rr*64 + col];
      }
      float gv = sigm(acc[cg][reg] + bgv);
      float hv = gv*hpv + (1.f-gv)*hnv;
      ushort_t hh = f2bf(hv);
      Ao[lrow][col] = hh;
      Ao[lrow][64+col] = f2bf(hv - bf2f(hh));
    }
  }
  __syncthreads();
  f32x4 acc2[4] = {z,z,z,z};
  #pragma unroll
  for (int ks = 0; ks < 6; ks++){
    int aoff = (ks < 2) ? ks*32 : (ks < 4) ? 64 + (ks-2)*32 : (ks-4)*32;
    int boff = (ks < 4) ? (ks & 1)*32 : 64 + (ks-4)*32;
    bf8 a = *(const bf8*)&Ao[w*16 + lr][aoff + 8*lg];
    #pragma unroll
    for (int cg = 0; cg < 4; cg++){
      bf8 b = *(const bf8*)&Bo[16*cg + lr][boff + 8*lg];
      acc2[cg] = MFMA(a, b, acc2[cg]);
    }
  }
  #pragma unroll
  for (int cg = 0; cg < 4; cg++){
    int col = 16*cg + lr;
    float bov = bo[col];
    #pragma unroll
    for (int reg = 0; reg < 4; reg++){
      int rr = r0 + w*16 + 4*lg + reg;
      if (rr < NN) h16[(size_t)rr*64 + col] = (f16)tanh_f(acc2[cg][reg] + bov);
    }
  }
}

// ---------------- edge MLP: register A-fragments, fp16 MFMA ----------------
__global__ __launch_bounds__(256) void k_edge(
    const f16* __restrict__ h16, const int* __restrict__ u, const int* __restrict__ v,
    const float* __restrict__ ts, const f16* __restrict__ Wt_e1h,
    const float* __restrict__ b_e1, const float* __restrict__ W_e2,
    const float* __restrict__ b_e2, float* __restrict__ out)
{
  __shared__ f16 Bl[64][296];
  int t = threadIdx.x;
  const uint4* W4 = (const uint4*)Wt_e1h;
  #pragma unroll
  for (int n = 0; n < 9; n++){
    int i = t + n*256; int row = i / 36, kc = i - row*36;
    *(uint4*)&Bl[row][kc*8] = W4[i];
  }
  int w = t >> 6, l = t & 63;
  int lr = l & 15, ksub = l >> 4;
  int eg = blockIdx.x*64 + w*16 + lr;
  int ue = u[eg], ve = v[eg];
  const h8* hu = (const h8*)(h16 + (size_t)ue*64 + ksub*8);
  const h8* hv = (const h8*)(h16 + (size_t)ve*64 + ksub*8);
  h8 ua0 = hu[0], ua1 = hu[4];
  h8 va0 = hv[0], va1 = hv[4];
  h8 d0 = habs8(ua0 - va0);
  h8 d1 = habs8(ua1 - va1);
  h8 p0 = ua0 * va0;
  h8 p1 = ua1 * va1;
  h8 tfv = {0,0,0,0,0,0,0,0};
  if (ksub < 2){
    float tt = ts[eg];
    tt = fminf(fmaxf(tt, 0.f), 1.f);
    #pragma unroll
    for (int j = 0; j < 8; j++){
      float ang = 3.14159265358979323846f * (float)(j+1) * tt;
      tfv[j] = (f16)(ksub == 0 ? __sinf(ang) : __cosf(ang));
    }
  }
  __syncthreads();
  f32x4 z4 = {0.f,0.f,0.f,0.f};
  f32x4 acc[4] = {z4,z4,z4,z4};
  int koff = ksub*8;
#define KSTEP(ks, afrag) { \
    h8 b0 = *(const h8*)&Bl[     lr][(ks)*32 + koff]; \
    h8 b1 = *(const h8*)&Bl[16 + lr][(ks)*32 + koff]; \
    h8 b2 = *(const h8*)&Bl[32 + lr][(ks)*32 + koff]; \
    h8 b3 = *(const h8*)&Bl[48 + lr][(ks)*32 + koff]; \
    acc[0] = MFMA16(afrag, b0, acc[0]); \
    acc[1] = MFMA16(afrag, b1, acc[1]); \
    acc[2] = MFMA16(afrag, b2, acc[2]); \
    acc[3] = MFMA16(afrag, b3, acc[3]); }
  KSTEP(0, ua0) KSTEP(1, ua1)
  KSTEP(2, va0) KSTEP(3, va1)
  KSTEP(4, d0)  KSTEP(5, d1)
  KSTEP(6, p0)  KSTEP(7, p1)
  KSTEP(8, tfv)
#undef KSTEP
  float bn[4], w2[4];
  #pragma unroll
  for (int nt = 0; nt < 4; nt++){
    bn[nt] = b_e1[nt*16 + lr];
    w2[nt] = W_e2[nt*16 + lr];
  }
  float be2 = b_e2[0];
  float4 res;
  #pragma unroll
  for (int reg = 0; reg < 4; reg++){
    float s = 0.f;
    #pragma unroll
    for (int nt = 0; nt < 4; nt++)
      s += fmaxf(acc[nt][reg] + bn[nt], 0.f) * w2[nt];
    s += __shfl_xor(s, 1);
    s += __shfl_xor(s, 2);
    s += __shfl_xor(s, 4);
    s += __shfl_xor(s, 8);
    (&res.x)[reg] = s + be2;
  }
  if (lr == 0)
    *(float4*)(out + blockIdx.x*64 + w*16 + 4*ksub) = res;
}

extern "C" void kernel_launch(void* const* d_in, const int* in_sizes, int n_in,
                              void* d_out, int out_size, void* d_ws, size_t ws_size,
                              hipStream_t stream)
{
  (void)in_sizes; (void)n_in; (void)out_size; (void)ws_size;
  const float* x       = (const float*)d_in[0];
  const int*   pos_row = (const int*)d_in[1];
  const int*   pos_col = (const int*)d_in[2];
  const float* pos_val = (const float*)d_in[3];
  const int*   neg_row = (const int*)d_in[4];
  const int*   neg_col = (const int*)d_in[5];
  const float* neg_val = (const float*)d_in[6];
  const int*   u       = (const int*)d_in[7];
  const int*   v       = (const int*)d_in[8];
  const float* ets     = (const float*)d_in[9];
  const float* W_in    = (const float*)d_in[10];
  const float* b_in    = (const float*)d_in[11];
  const float* W_gate  = (const float*)d_in[12];
  const float* b_gate  = (const float*)d_in[13];
  const float* W_out   = (const float*)d_in[14];
  const float* b_out   = (const float*)d_in[15];
  const float* W_e1    = (const float*)d_in[16];
  const float* b_e1    = (const float*)d_in[17];
  const float* W_e2    = (const float*)d_in[18];
  const float* b_e2    = (const float*)d_in[19];
  float* out = (float*)d_out;

  char* wsb = (char*)d_ws;
  size_t off = 0;
  auto alloc = [&](size_t bytes)->char*{
    char* pp = wsb + off; off += (bytes + 255) & ~(size_t)255; return pp;
  };
  f16*      h16   = (f16*)alloc((size_t)NN*64*2);
  float*    hp    = (float*)alloc((size_t)NN*64*4);   // aliases tmp_p (dead after k_csr)
  float*    hn    = (float*)alloc((size_t)NN*64*4);   // aliases tmp_n
  uint2*    tmp_p = (uint2*)hp;
  uint2*    tmp_n = (uint2*)hn;
  unsigned* csr_p = (unsigned*)alloc((size_t)NNZq*4);
  unsigned* csr_n = (unsigned*)alloc((size_t)NNZq*4);
  int*      blkhist = (int*)alloc((size_t)2*NBLK*NBUCK*4);
  int*      btot  = (int*)alloc((size_t)2*NBUCK*4);
  int*      bbase = (int*)alloc((size_t)2*(NBUCK+1)*4);
  int*      rowptr= (int*)alloc((size_t)2*RSTR*4);
  ushort_t* Wt_in = (ushort_t*)alloc(64*512*2);
  ushort_t* Wgt   = (ushort_t*)alloc(2*64*256*2);
  ushort_t* Wot   = (ushort_t*)alloc(2*64*128*2);
  f16*      Wt_e1h= (f16*)alloc(64*288*2);

  k_prep<<<64, 256, 0, stream>>>(W_in, W_gate, W_out, W_e1, Wt_in, Wgt, Wot, Wt_e1h);

  k_cnt<<<dim3(NBLK, 2), 256, 0, stream>>>(pos_row, neg_row, blkhist);
  k_scanA<<<dim3(NBUCK, 2), 256, 0, stream>>>(blkhist, btot);
  k_scanB<<<dim3(1, 2), 1024, 0, stream>>>(btot, bbase);
  // fused scat+embed, interleaved block types: 2*1250 alternating + 313 embed tail
  k_scatembed<<<2*NBLK*2 + (NEMB - 2*NBLK), 256, 0, stream>>>(
      pos_row, pos_col, pos_val, neg_row, neg_col, neg_val,
      blkhist, bbase, tmp_p, tmp_n,
      x, Wt_in, b_in, h16);
  k_csr<<<dim3(NBUCK, 2), 256, 0, stream>>>(bbase, tmp_p, tmp_n, csr_p, csr_n, rowptr);

  for (int hop = 0; hop < 2; hop++){
    k_spmm2<<<NN/4, 256, 0, stream>>>(rowptr, csr_p, rowptr + RSTR, csr_n, h16, hp, hn);
    k_gateout<<<1563, 256, 0, stream>>>(hp, hn,
        Wgt + (size_t)hop*16384, Wot + (size_t)hop*8192,
        b_gate + hop*64, b_out + hop*64, h16);
  }
  k_edge<<<NE/64, 256, 0, stream>>>(h16, u, v, ets, Wt_e1h, b_e1, W_e2, b_e2, out);
}

// Round 18
// 507.849 us; speedup vs baseline: 1.0552x; 1.0552x over previous
//
#include <hip/hip_runtime.h>

#define NN   100000
#define NNZq 3200000
#define NE   1000000
#define NBUCK 782        // ceil(NN/128) buckets of 128 rows
#define NBLK  500        // chunks over the COO arrays
#define CHUNK 6400       // NBLK*CHUNK == NNZq
#define BCAP 5120        // k_csr LDS stage capacity
#define RSTR 100032      // int stride between pos/neg rowptr arrays

typedef float f32x4 __attribute__((ext_vector_type(4)));
typedef unsigned short ushort_t;
typedef ushort_t us4 __attribute__((ext_vector_type(4)));
typedef ushort_t us8 __attribute__((ext_vector_type(8)));
typedef __bf16 bf8 __attribute__((ext_vector_type(8)));
typedef _Float16 f16;
typedef f16 h8 __attribute__((ext_vector_type(8)));

__device__ __forceinline__ ushort_t f2bf(float f){
  unsigned u = __builtin_bit_cast(unsigned, f);
  u += 0x7FFFu + ((u >> 16) & 1u);
  return (ushort_t)(u >> 16);
}
__device__ __forceinline__ float bf2f(ushort_t s){
  unsigned u = ((unsigned)s) << 16;
  return __builtin_bit_cast(float, u);
}
__device__ __forceinline__ float sigm(float x){ return 1.f/(1.f + __expf(-x)); }
__device__ __forceinline__ float tanh_f(float x){ return 1.f - 2.f/(1.f + __expf(2.f*x)); }

__device__ __forceinline__ f32x4 MFMA(bf8 a, bf8 b, f32x4 c){
  return __builtin_amdgcn_mfma_f32_16x16x32_bf16(a, b, c, 0, 0, 0);
}
__device__ __forceinline__ f32x4 MFMA16(h8 a, h8 b, f32x4 c){
  return __builtin_amdgcn_mfma_f32_16x16x32_f16(a, b, c, 0, 0, 0);
}
__device__ __forceinline__ h8 habs8(h8 a){
  us8 u = __builtin_bit_cast(us8, a);
  #pragma unroll
  for (int j = 0; j < 8; j++) u[j] = u[j] & 0x7FFF;
  return __builtin_bit_cast(h8, u);
}
// bijective XCD-contiguous chunk swizzle (NBLK=500: q=62, r=4)
__device__ __forceinline__ int swz_chunk(int bid){
  int g = bid & 7, j = bid >> 3;
  const int q = NBLK >> 3, r = NBLK & 7;
  int base = (g < r) ? g*(q+1) : r*(q+1) + (g - r)*q;
  return base + j;
}
// convert 8 floats to split-bf16 hi/lo fragments
__device__ __forceinline__ void splitbf(const float* fv, bf8& hi8, bf8& lo8){
  us8 hi, lo;
  #pragma unroll
  for (int j = 0; j < 8; j++){
    ushort_t hh = f2bf(fv[j]); hi[j] = hh; lo[j] = f2bf(fv[j] - bf2f(hh));
  }
  hi8 = __builtin_bit_cast(bf8, hi);
  lo8 = __builtin_bit_cast(bf8, lo);
}

// ---------------- weight prep ----------------
__global__ __launch_bounds__(256) void k_prep(
    const float* __restrict__ W_in, const float* __restrict__ W_gate,
    const float* __restrict__ W_out, const float* __restrict__ W_e1,
    ushort_t* __restrict__ Wt_in, ushort_t* __restrict__ Wgt,
    ushort_t* __restrict__ Wot, f16* __restrict__ Wt_e1h)
{
  int tid = blockIdx.x * 256 + threadIdx.x;
  int stride = gridDim.x * 256;
  for (int i = tid; i < 64*256; i += stride){
    int c = i >> 8, k = i & 255;
    float f = W_in[k*64 + c];
    ushort_t hi = f2bf(f); ushort_t lo = f2bf(f - bf2f(hi));
    Wt_in[c*512 + k] = hi; Wt_in[c*512 + 256 + k] = lo;
  }
  for (int i = tid; i < 2*64*128; i += stride){
    int hop = i >> 13, r = i & 8191; int c = r >> 7, k = r & 127;
    float f = W_gate[hop*8192 + k*64 + c];
    ushort_t hi = f2bf(f); ushort_t lo = f2bf(f - bf2f(hi));
    Wgt[hop*16384 + c*256 + k] = hi; Wgt[hop*16384 + c*256 + 128 + k] = lo;
  }
  for (int i = tid; i < 2*64*64; i += stride){
    int hop = i >> 12, r = i & 4095; int c = r >> 6, k = r & 63;
    float f = W_out[hop*4096 + k*64 + c];
    ushort_t hi = f2bf(f); ushort_t lo = f2bf(f - bf2f(hi));
    Wot[hop*8192 + c*128 + k] = hi; Wot[hop*8192 + c*128 + 64 + k] = lo;
  }
  for (int i = tid; i < 64*288; i += stride){
    int c = i / 288, k = i - c*288;
    float f = (k < 272) ? W_e1[k*64 + c] : 0.f;
    Wt_e1h[c*288 + k] = (f16)f;
  }
}

// ---------------- counting sort, pass 1 ----------------
__global__ __launch_bounds__(256) void k_cnt(
    const int* __restrict__ rows_p, const int* __restrict__ rows_n,
    int* __restrict__ blkhist)
{
  __shared__ int hist[NBUCK];
  const int* rows = blockIdx.y ? rows_n : rows_p;
  int* bh = blkhist + (size_t)blockIdx.y * (NBLK*NBUCK);
  int t = threadIdx.x;
  for (int i = t; i < NBUCK; i += 256) hist[i] = 0;
  __syncthreads();
  int base = blockIdx.x * CHUNK;
  #pragma unroll
  for (int k = 0; k < CHUNK/256; k++){
    int r = rows[base + t + k*256];
    atomicAdd(&hist[r >> 7], 1);
  }
  __syncthreads();
  for (int i = t; i < NBUCK; i += 256) bh[blockIdx.x * NBUCK + i] = hist[i];
}

__global__ __launch_bounds__(256) void k_scanA(int* __restrict__ blkhist, int* __restrict__ btot)
{
  __shared__ int sh[256];
  int b = blockIdx.x;
  int* bh = blkhist + (size_t)blockIdx.y * (NBLK*NBUCK);
  int t = threadIdx.x;
  int carry = 0;
  for (int k0 = 0; k0 < NBLK; k0 += 256){
    int idx = k0 + t;
    int v = (idx < NBLK) ? bh[idx*NBUCK + b] : 0;
    sh[t] = v; __syncthreads();
    for (int off = 1; off < 256; off <<= 1){
      int xx = (t >= off) ? sh[t-off] : 0;
      __syncthreads();
      sh[t] += xx;
      __syncthreads();
    }
    if (idx < NBLK) bh[idx*NBUCK + b] = carry + sh[t] - v;
    carry += sh[255];
    __syncthreads();
  }
  if (t == 0) btot[blockIdx.y*NBUCK + b] = carry;
}

__global__ __launch_bounds__(1024) void k_scanB(const int* __restrict__ btot, int* __restrict__ bbase)
{
  __shared__ int sh[1024];
  int y = blockIdx.y;
  int t = threadIdx.x;
  int v = (t < NBUCK) ? btot[y*NBUCK + t] : 0;
  sh[t] = v; __syncthreads();
  for (int off = 1; off < 1024; off <<= 1){
    int xx = (t >= off) ? sh[t-off] : 0;
    __syncthreads();
    sh[t] += xx;
    __syncthreads();
  }
  if (t < NBUCK) bbase[y*(NBUCK+1) + t] = sh[t] - v;
  if (t == 0) bbase[y*(NBUCK+1) + NBUCK] = sh[1023];
}

// ---------------- fused: scat (blocks 0..2*NBLK-1) + embed (blocks 2*NBLK..) ----------------
// scat LDS: stage 51200 | hcnt 3136 | lcur 3136 | sh 1024  = 58496 B
// embed LDS: Bl[64][520] ushort = 66560 B
#define SMEM_BYTES 66560
__global__ __launch_bounds__(256) void k_scatembed(
    // scat args
    const int* __restrict__ rows_p, const int* __restrict__ cols_p, const float* __restrict__ vals_p,
    const int* __restrict__ rows_n, const int* __restrict__ cols_n, const float* __restrict__ vals_n,
    const int* __restrict__ blkhist, const int* __restrict__ bbase,
    uint2* __restrict__ tmp_p, uint2* __restrict__ tmp_n,
    // embed args
    const float* __restrict__ x, const ushort_t* __restrict__ Wt,
    const float* __restrict__ b_in, f16* __restrict__ h16)
{
  __shared__ __align__(16) char smem[SMEM_BYTES];
  int t = threadIdx.x;
  if (blockIdx.x < 2*NBLK){
    // ---------- scat ----------
    uint2* stage = (uint2*)smem;
    int* hcnt = (int*)(smem + 51200);
    int* lcur = (int*)(smem + 51200 + 3136);
    int* sh   = (int*)(smem + 51200 + 3136*2);
    int y = (blockIdx.x >= NBLK) ? 1 : 0;
    int bx = blockIdx.x - y*NBLK;
    const int* rows; const int* cols; const float* vals; uint2* tmp;
    if (y == 0){ rows = rows_p; cols = cols_p; vals = vals_p; tmp = tmp_p; }
    else       { rows = rows_n; cols = cols_n; vals = vals_n; tmp = tmp_n; }
    int chunk = swz_chunk(bx);
    const int* bh = blkhist + (size_t)y*(NBLK*NBUCK) + (size_t)chunk*NBUCK;
    const int* bb = bbase + y*(NBUCK+1);
    for (int i = t; i < NBUCK; i += 256) hcnt[i] = 0;
    __syncthreads();
    int base = chunk * CHUNK;
    int rl[CHUNK/256];
    #pragma unroll
    for (int k = 0; k < CHUNK/256; k++){
      int r = rows[base + t + k*256];
      rl[k] = r;
      atomicAdd(&hcnt[r >> 7], 1);
    }
    __syncthreads();
    int carry = 0;
    for (int k0 = 0; k0 < 1024; k0 += 256){
      int idx = k0 + t;
      int v = (idx < NBUCK) ? hcnt[idx] : 0;
      sh[t] = v; __syncthreads();
      for (int off = 1; off < 256; off <<= 1){
        int xx = (t >= off) ? sh[t-off] : 0;
        __syncthreads();
        sh[t] += xx;
        __syncthreads();
      }
      if (idx < NBUCK) lcur[idx] = carry + sh[t] - v;
      carry += sh[255];
      __syncthreads();
    }
    for (int i = t; i < NBUCK; i += 256) hcnt[i] = bb[i] + bh[i] - lcur[i];
    __syncthreads();
    #pragma unroll
    for (int k = 0; k < CHUNK/256; k++){
      int i = base + t + k*256;
      int r = rl[k];
      int pos = atomicAdd(&lcur[r >> 7], 1);
      f16 hv = (f16)vals[i];
      uint2 ent;
      ent.x = (unsigned)cols[i] | ((unsigned)(r & 127) << 17);
      ent.y = (unsigned)__builtin_bit_cast(ushort_t, hv) | ((unsigned)(r >> 7) << 16);
      stage[pos] = ent;
    }
    __syncthreads();
    for (int k = t; k < CHUNK; k += 256){
      uint2 ent = stage[k];
      int bkt = ent.y >> 16;
      tmp[hcnt[bkt] + k] = ent;
    }
  } else {
    // ---------- embed ----------
    ushort_t (*Bl)[520] = (ushort_t(*)[520])smem;
    int eb = blockIdx.x - 2*NBLK;
    int r0 = eb * 64;
    const uint4* W4 = (const uint4*)Wt;
    #pragma unroll
    for (int n = 0; n < 16; n++){
      int i = t + n*256;
      int row = i >> 6, kc = i & 63;
      *(uint4*)&Bl[row][kc*8] = W4[i];
    }
    int w = t >> 6, l = t & 63;
    int lr = l & 15, lg = l >> 4;
    int row = r0 + w*16 + lr;
    bool ok = row < NN;
    const float* xr = x + (size_t)row*256 + lg*8;
    bf8 ahi[8], alo[8];
    #pragma unroll
    for (int ks = 0; ks < 8; ks++){
      float4 v0 = make_float4(0.f,0.f,0.f,0.f), v1 = v0;
      if (ok){
        v0 = *(const float4*)(xr + ks*32);
        v1 = *(const float4*)(xr + ks*32 + 4);
      }
      float fv[8] = {v0.x,v0.y,v0.z,v0.w,v1.x,v1.y,v1.z,v1.w};
      splitbf(fv, ahi[ks], alo[ks]);
    }
    __syncthreads();
    f32x4 z = {0.f,0.f,0.f,0.f};
    f32x4 acc[4] = {z,z,z,z};
    #pragma unroll
    for (int ks = 0; ks < 24; ks++){
      bf8 a = (ks < 8) ? ahi[ks] : (ks < 16) ? alo[ks-8] : ahi[ks-16];
      int boff = (ks < 16) ? (ks & 7)*32 : 256 + (ks-16)*32;
      #pragma unroll
      for (int cg = 0; cg < 4; cg++){
        bf8 b = *(const bf8*)&Bl[16*cg + lr][boff + 8*lg];
        acc[cg] = MFMA(a, b, acc[cg]);
      }
    }
    #pragma unroll
    for (int cg = 0; cg < 4; cg++){
      int col = 16*cg + lr;
      float bi = b_in[col];
      #pragma unroll
      for (int reg = 0; reg < 4; reg++){
        int rr = r0 + w*16 + 4*lg + reg;
        if (rr < NN) h16[(size_t)rr*64 + col] = (f16)tanh_f(acc[cg][reg] + bi);
      }
    }
  }
}

// ---------------- pass 4: bucket-grouped -> row-sorted 4B CSR + rowptr (round-9 version) ----------------
// CSR entry: (col & 0x1FFFF) | (f16bits(val) << 17)
__global__ __launch_bounds__(256) void k_csr(
    const int* __restrict__ bbase, const uint2* __restrict__ tmp_p, const uint2* __restrict__ tmp_n,
    unsigned* __restrict__ csr_p, unsigned* __restrict__ csr_n, int* __restrict__ rowptr)
{
  __shared__ int cnt[128];
  __shared__ int sh[128];
  __shared__ int lcur[128];
  __shared__ unsigned stage[BCAP];
  int y = blockIdx.y, b = blockIdx.x;
  const uint2* tmp = y ? tmp_n : tmp_p;
  unsigned* csr = y ? csr_n : csr_p;
  int* rp = rowptr + (size_t)y * RSTR;
  const int* bb = bbase + y*(NBUCK+1);
  int s = bb[b], e = bb[b+1];
  int n = e - s;
  int t = threadIdx.x;
  if (t < 128) cnt[t] = 0;
  __syncthreads();
  for (int k = t; k < n; k += 256)
    atomicAdd(&cnt[tmp[s + k].x >> 17], 1);
  __syncthreads();
  if (t < 128) sh[t] = cnt[t];
  __syncthreads();
  for (int off = 1; off < 128; off <<= 1){
    int xx = (t >= off && t < 128) ? sh[t-off] : 0;
    __syncthreads();
    if (t < 128) sh[t] += xx;
    __syncthreads();
  }
  if (t < 128){
    int excl = sh[t] - cnt[t];
    lcur[t] = excl;
    int row = b*128 + t;
    if (row < NN) rp[row] = s + excl;
  }
  if (b == NBUCK-1 && t == 0) rp[NN] = e;
  __syncthreads();
  if (n <= BCAP){
    for (int k = t; k < n; k += 256){
      uint2 ent = tmp[s + k];
      int rloc = ent.x >> 17;
      int pos = atomicAdd(&lcur[rloc], 1);
      stage[pos] = (ent.x & 0x1FFFF) | ((ent.y & 0xFFFFu) << 17);
    }
    __syncthreads();
    for (int k = t; k < n; k += 256) csr[s + k] = stage[k];
  } else {
    for (int k = t; k < n; k += 256){
      uint2 ent = tmp[s + k];
      int rloc = ent.x >> 17;
      int pos = atomicAdd(&lcur[rloc], 1);
      csr[s + pos] = (ent.x & 0x1FFFF) | ((ent.y & 0xFFFFu) << 17);
    }
  }
}

// ---------------- SpMM fused pos+neg: one wave per row, 4B entries, fp16 gathers ----------------
__device__ __forceinline__ float ent_val(unsigned e){
  return (float)__builtin_bit_cast(f16, (ushort_t)(e >> 17));
}
__global__ __launch_bounds__(256) void k_spmm2(
    const int* __restrict__ rp_p, const unsigned* __restrict__ csr_p,
    const int* __restrict__ rp_n, const unsigned* __restrict__ csr_n,
    const f16* __restrict__ h16, float* __restrict__ hp, float* __restrict__ hn)
{
  int w = __builtin_amdgcn_readfirstlane(blockIdx.x * 4 + (threadIdx.x >> 6));
  int l = threadIdx.x & 63;
  int sp = __builtin_amdgcn_readfirstlane(rp_p[w]);
  int ep = __builtin_amdgcn_readfirstlane(rp_p[w+1]);
  int sn = __builtin_amdgcn_readfirstlane(rp_n[w]);
  int en = __builtin_amdgcn_readfirstlane(rp_n[w+1]);
  float ap = 0.f, an = 0.f;
  int i = sp, j = sn;
  while (i + 4 <= ep && j + 4 <= en){
    unsigned q0 = csr_p[i], q1 = csr_p[i+1], q2 = csr_p[i+2], q3 = csr_p[i+3];
    unsigned r0 = csr_n[j], r1 = csr_n[j+1], r2 = csr_n[j+2], r3 = csr_n[j+3];
    float g0 = (float)h16[(q0 & 0x1FFFF)*64 + l], g1 = (float)h16[(q1 & 0x1FFFF)*64 + l];
    float g2 = (float)h16[(q2 & 0x1FFFF)*64 + l], g3 = (float)h16[(q3 & 0x1FFFF)*64 + l];
    float f0 = (float)h16[(r0 & 0x1FFFF)*64 + l], f1 = (float)h16[(r1 & 0x1FFFF)*64 + l];
    float f2 = (float)h16[(r2 & 0x1FFFF)*64 + l], f3 = (float)h16[(r3 & 0x1FFFF)*64 + l];
    ap += ent_val(q0) * g0;
    ap += ent_val(q1) * g1;
    ap += ent_val(q2) * g2;
    ap += ent_val(q3) * g3;
    an += ent_val(r0) * f0;
    an += ent_val(r1) * f1;
    an += ent_val(r2) * f2;
    an += ent_val(r3) * f3;
    i += 4; j += 4;
  }
  for (; i + 4 <= ep; i += 4){
    unsigned q0 = csr_p[i], q1 = csr_p[i+1], q2 = csr_p[i+2], q3 = csr_p[i+3];
    float g0 = (float)h16[(q0 & 0x1FFFF)*64 + l], g1 = (float)h16[(q1 & 0x1FFFF)*64 + l];
    float g2 = (float)h16[(q2 & 0x1FFFF)*64 + l], g3 = (float)h16[(q3 & 0x1FFFF)*64 + l];
    ap += ent_val(q0) * g0;
    ap += ent_val(q1) * g1;
    ap += ent_val(q2) * g2;
    ap += ent_val(q3) * g3;
  }
  for (; i < ep; i++){
    unsigned q = csr_p[i];
    ap += ent_val(q) * (float)h16[(q & 0x1FFFF)*64 + l];
  }
  for (; j + 4 <= en; j += 4){
    unsigned r0 = csr_n[j], r1 = csr_n[j+1], r2 = csr_n[j+2], r3 = csr_n[j+3];
    float f0 = (float)h16[(r0 & 0x1FFFF)*64 + l], f1 = (float)h16[(r1 & 0x1FFFF)*64 + l];
    float f2 = (float)h16[(r2 & 0x1FFFF)*64 + l], f3 = (float)h16[(r3 & 0x1FFFF)*64 + l];
    an += ent_val(r0) * f0;
    an += ent_val(r1) * f1;
    an += ent_val(r2) * f2;
    an += ent_val(r3) * f3;
  }
  for (; j < en; j++){
    unsigned r = csr_n[j];
    an += ent_val(r) * (float)h16[(r & 0x1FFFF)*64 + l];
  }
  hp[w*64 + l] = ap;
  hn[w*64 + l] = an;
}

// ---------------- gate+out per hop: reg-A split-bf16 MFMA, writes fp16 h ----------------
__global__ __launch_bounds__(256) void k_gateout(
    const float* __restrict__ hp, const float* __restrict__ hn,
    const ushort_t* __restrict__ Wgt_h, const ushort_t* __restrict__ Wot_h,
    const float* __restrict__ bg, const float* __restrict__ bo,
    f16* __restrict__ h16)
{
  __shared__ ushort_t Bg[64][264];
  __shared__ ushort_t Ao[64][136];
  __shared__ ushort_t Bo[64][136];
  int t = threadIdx.x;
  int r0 = blockIdx.x * 64;
  const uint4* Wg4 = (const uint4*)Wgt_h;
  #pragma unroll
  for (int n = 0; n < 8; n++){
    int i = t + n*256; int row = i >> 5, kc = i & 31;
    *(uint4*)&Bg[row][kc*8] = Wg4[i];
  }
  const uint4* Wo4 = (const uint4*)Wot_h;
  #pragma unroll
  for (int n = 0; n < 4; n++){
    int i = t + n*256; int row = i >> 4, kc = i & 15;
    *(uint4*)&Bo[row][kc*8] = Wo4[i];
  }
  int w = t >> 6, l = t & 63;
  int lr = l & 15, lg = l >> 4;
  int arow = r0 + w*16 + lr;
  bool ok = arow < NN;
  const float* hpr = hp + (size_t)arow*64 + lg*8;
  const float* hnr = hn + (size_t)arow*64 + lg*8;
  bf8 ahi[4], alo[4];
  #pragma unroll
  for (int ks = 0; ks < 4; ks++){
    const float* src = (ks < 2) ? hpr + ks*32 : hnr + (ks-2)*32;
    float4 v0 = make_float4(0.f,0.f,0.f,0.f), v1 = v0;
    if (ok){
      v0 = *(const float4*)src;
      v1 = *(const float4*)(src + 4);
    }
    float fv[8] = {v0.x,v0.y,v0.z,v0.w,v1.x,v1.y,v1.z,v1.w};
    splitbf(fv, ahi[ks], alo[ks]);
  }
  __syncthreads();
  f32x4 z = {0.f,0.f,0.f,0.f};
  f32x4 acc[4] = {z,z,z,z};
  #pragma unroll
  for (int ks = 0; ks < 12; ks++){
    bf8 a = (ks < 4) ? ahi[ks] : (ks < 8) ? alo[ks-4] : ahi[ks-8];
    int boff = (ks < 8) ? (ks & 3)*32 : 128 + (ks-8)*32;
    #pragma unroll
    for (int cg = 0; cg < 4; cg++){
      bf8 b = *(const bf8*)&Bg[16*cg + lr][boff + 8*lg];
      acc[cg] = MFMA(a, b, acc[cg]);
    }
  }
  #pragma unroll
  for (int cg = 0; cg < 4; cg++){
    int col = 16*cg + lr;
    float bgv = bg[col];
    #pragma unroll
    for (int reg = 0; reg < 4; reg++){
      int lrow = w*16 + 4*lg + reg;
      int rr = r0 + lrow;
      float hpv = 0.f, hnv = 0.f;
      if (rr < NN){
        hpv = hp[(size_t)rr*64 + col];
        hnv = hn[(size_t)rr*64 + col];
      }
      float gv = sigm(acc[cg][reg] + bgv);
      float hv = gv*hpv + (1.f-gv)*hnv;
      ushort_t hh = f2bf(hv);
      Ao[lrow][col] = hh;
      Ao[lrow][64+col] = f2bf(hv - bf2f(hh));
    }
  }
  __syncthreads();
  f32x4 acc2[4] = {z,z,z,z};
  #pragma unroll
  for (int ks = 0; ks < 6; ks++){
    int aoff = (ks < 2) ? ks*32 : (ks < 4) ? 64 + (ks-2)*32 : (ks-4)*32;
    int boff = (ks < 4) ? (ks & 1)*32 : 64 + (ks-4)*32;
    bf8 a = *(const bf8*)&Ao[w*16 + lr][aoff + 8*lg];
    #pragma unroll
    for (int cg = 0; cg < 4; cg++){
      bf8 b = *(const bf8*)&Bo[16*cg + lr][boff + 8*lg];
      acc2[cg] = MFMA(a, b, acc2[cg]);
    }
  }
  #pragma unroll
  for (int cg = 0; cg < 4; cg++){
    int col = 16*cg + lr;
    float bov = bo[col];
    #pragma unroll
    for (int reg = 0; reg < 4; reg++){
      int rr = r0 + w*16 + 4*lg + reg;
      if (rr < NN) h16[(size_t)rr*64 + col] = (f16)tanh_f(acc2[cg][reg] + bov);
    }
  }
}

// ---------------- edge MLP: register A-fragments, fp16 MFMA ----------------
__global__ __launch_bounds__(256) void k_edge(
    const f16* __restrict__ h16, const int* __restrict__ u, const int* __restrict__ v,
    const float* __restrict__ ts, const f16* __restrict__ Wt_e1h,
    const float* __restrict__ b_e1, const float* __restrict__ W_e2,
    const float* __restrict__ b_e2, float* __restrict__ out)
{
  __shared__ f16 Bl[64][296];
  int t = threadIdx.x;
  const uint4* W4 = (const uint4*)Wt_e1h;
  #pragma unroll
  for (int n = 0; n < 9; n++){
    int i = t + n*256; int row = i / 36, kc = i - row*36;
    *(uint4*)&Bl[row][kc*8] = W4[i];
  }
  int w = t >> 6, l = t & 63;
  int lr = l & 15, ksub = l >> 4;
  int eg = blockIdx.x*64 + w*16 + lr;
  int ue = u[eg], ve = v[eg];
  const h8* hu = (const h8*)(h16 + (size_t)ue*64 + ksub*8);
  const h8* hv = (const h8*)(h16 + (size_t)ve*64 + ksub*8);
  h8 ua0 = hu[0], ua1 = hu[4];
  h8 va0 = hv[0], va1 = hv[4];
  h8 d0 = habs8(ua0 - va0);
  h8 d1 = habs8(ua1 - va1);
  h8 p0 = ua0 * va0;
  h8 p1 = ua1 * va1;
  h8 tfv = {0,0,0,0,0,0,0,0};
  if (ksub < 2){
    float tt = ts[eg];
    tt = fminf(fmaxf(tt, 0.f), 1.f);
    #pragma unroll
    for (int j = 0; j < 8; j++){
      float ang = 3.14159265358979323846f * (float)(j+1) * tt;
      tfv[j] = (f16)(ksub == 0 ? __sinf(ang) : __cosf(ang));
    }
  }
  __syncthreads();
  f32x4 z4 = {0.f,0.f,0.f,0.f};
  f32x4 acc[4] = {z4,z4,z4,z4};
  int koff = ksub*8;
#define KSTEP(ks, afrag) { \
    h8 b0 = *(const h8*)&Bl[     lr][(ks)*32 + koff]; \
    h8 b1 = *(const h8*)&Bl[16 + lr][(ks)*32 + koff]; \
    h8 b2 = *(const h8*)&Bl[32 + lr][(ks)*32 + koff]; \
    h8 b3 = *(const h8*)&Bl[48 + lr][(ks)*32 + koff]; \
    acc[0] = MFMA16(afrag, b0, acc[0]); \
    acc[1] = MFMA16(afrag, b1, acc[1]); \
    acc[2] = MFMA16(afrag, b2, acc[2]); \
    acc[3] = MFMA16(afrag, b3, acc[3]); }
  KSTEP(0, ua0) KSTEP(1, ua1)
  KSTEP(2, va0) KSTEP(3, va1)
  KSTEP(4, d0)  KSTEP(5, d1)
  KSTEP(6, p0)  KSTEP(7, p1)
  KSTEP(8, tfv)
#undef KSTEP
  float bn[4], w2[4];
  #pragma unroll
  for (int nt = 0; nt < 4; nt++){
    bn[nt] = b_e1[nt*16 + lr];
    w2[nt] = W_e2[nt*16 + lr];
  }
  float be2 = b_e2[0];
  float4 res;
  #pragma unroll
  for (int reg = 0; reg < 4; reg++){
    float s = 0.f;
    #pragma unroll
    for (int nt = 0; nt < 4; nt++)
      s += fmaxf(acc[nt][reg] + bn[nt], 0.f) * w2[nt];
    s += __shfl_xor(s, 1);
    s += __shfl_xor(s, 2);
    s += __shfl_xor(s, 4);
    s += __shfl_xor(s, 8);
    (&res.x)[reg] = s + be2;
  }
  if (lr == 0)
    *(float4*)(out + blockIdx.x*64 + w*16 + 4*ksub) = res;
}

extern "C" void kernel_launch(void* const* d_in, const int* in_sizes, int n_in,
                              void* d_out, int out_size, void* d_ws, size_t ws_size,
                              hipStream_t stream)
{
  (void)in_sizes; (void)n_in; (void)out_size; (void)ws_size;
  const float* x       = (const float*)d_in[0];
  const int*   pos_row = (const int*)d_in[1];
  const int*   pos_col = (const int*)d_in[2];
  const float* pos_val = (const float*)d_in[3];
  const int*   neg_row = (const int*)d_in[4];
  const int*   neg_col = (const int*)d_in[5];
  const float* neg_val = (const float*)d_in[6];
  const int*   u       = (const int*)d_in[7];
  const int*   v       = (const int*)d_in[8];
  const float* ets     = (const float*)d_in[9];
  const float* W_in    = (const float*)d_in[10];
  const float* b_in    = (const float*)d_in[11];
  const float* W_gate  = (const float*)d_in[12];
  const float* b_gate  = (const float*)d_in[13];
  const float* W_out   = (const float*)d_in[14];
  const float* b_out   = (const float*)d_in[15];
  const float* W_e1    = (const float*)d_in[16];
  const float* b_e1    = (const float*)d_in[17];
  const float* W_e2    = (const float*)d_in[18];
  const float* b_e2    = (const float*)d_in[19];
  float* out = (float*)d_out;

  char* wsb = (char*)d_ws;
  size_t off = 0;
  auto alloc = [&](size_t bytes)->char*{
    char* pp = wsb + off; off += (bytes + 255) & ~(size_t)255; return pp;
  };
  f16*      h16   = (f16*)alloc((size_t)NN*64*2);
  float*    hp    = (float*)alloc((size_t)NN*64*4);   // aliases tmp_p (dead after k_csr)
  float*    hn    = (float*)alloc((size_t)NN*64*4);   // aliases tmp_n
  uint2*    tmp_p = (uint2*)hp;
  uint2*    tmp_n = (uint2*)hn;
  unsigned* csr_p = (unsigned*)alloc((size_t)NNZq*4);
  unsigned* csr_n = (unsigned*)alloc((size_t)NNZq*4);
  int*      blkhist = (int*)alloc((size_t)2*NBLK*NBUCK*4);
  int*      btot  = (int*)alloc((size_t)2*NBUCK*4);
  int*      bbase = (int*)alloc((size_t)2*(NBUCK+1)*4);
  int*      rowptr= (int*)alloc((size_t)2*RSTR*4);
  ushort_t* Wt_in = (ushort_t*)alloc(64*512*2);
  ushort_t* Wgt   = (ushort_t*)alloc(2*64*256*2);
  ushort_t* Wot   = (ushort_t*)alloc(2*64*128*2);
  f16*      Wt_e1h= (f16*)alloc(64*288*2);

  k_prep<<<64, 256, 0, stream>>>(W_in, W_gate, W_out, W_e1, Wt_in, Wgt, Wot, Wt_e1h);

  k_cnt<<<dim3(NBLK, 2), 256, 0, stream>>>(pos_row, neg_row, blkhist);
  k_scanA<<<dim3(NBUCK, 2), 256, 0, stream>>>(blkhist, btot);
  k_scanB<<<dim3(1, 2), 1024, 0, stream>>>(btot, bbase);
  // fused: scat (1000 blocks) + embed (1563 blocks), independent work co-scheduled
  k_scatembed<<<2*NBLK + 1563, 256, 0, stream>>>(
      pos_row, pos_col, pos_val, neg_row, neg_col, neg_val,
      blkhist, bbase, tmp_p, tmp_n,
      x, Wt_in, b_in, h16);
  k_csr<<<dim3(NBUCK, 2), 256, 0, stream>>>(bbase, tmp_p, tmp_n, csr_p, csr_n, rowptr);

  for (int hop = 0; hop < 2; hop++){
    k_spmm2<<<NN/4, 256, 0, stream>>>(rowptr, csr_p, rowptr + RSTR, csr_n, h16, hp, hn);
    k_gateout<<<1563, 256, 0, stream>>>(hp, hn,
        Wgt + (size_t)hop*16384, Wot + (size_t)hop*8192,
        b_gate + hop*64, b_out + hop*64, h16);
  }
  k_edge<<<NE/64, 256, 0, stream>>>(h16, u, v, ets, Wt_e1h, b_e1, W_e2, b_e2, out);
}